// Round 14
// baseline (134.258 us; speedup 1.0000x reference)
//
#include <hip/hip_runtime.h>

// STFT: x[16, 262144] fp32, Hann 2048, hop 512, reflect pad 1024.
// Output: real[16,1025,513] ++ imag[16,1025,513], fp32.
//
// Round 21: barrier-free register-resident FFT (orthogonal structure).
// The R20 floor is the barrier-phased LDS round-trip chain; this kernel
// removes LDS and barriers entirely. One wave = one plane (2 packed frames),
// 2048 points in registers (32 float2/lane), Bailey four-step N = 64 x 32:
//   n = n1 + 64*n2 (n1 = lane, n2 = reg)
//   1) 32-pt DIF FFT over regs (lane-local, constant twiddle table);
//      output Y(k2) at reg bitrev5(k2).
//   2) twiddle W_2048^{l*k2} (1 sincos + 31-cmul recurrence).
//   3) 64-pt DIF FFT across lanes via __shfl_xor (6 stages, 1 sincos each);
//      output X[k2+32*k1] with k1 = bitrev6(lane).
//   4) conjugate-symmetry epilogue in-wave: X[2048-k] = reg bitrev5(32-k2)
//      of lane l^63 (k2>0, one shfl_xor); k2==0 via one bpermute. Even
//      lanes store rows k = k2+32*k1 (k1<=31); lane 1 stores k=1024.
// Zero barriers, zero LDS. 4112 independent waves = 1028 blocks x 256 thr
// (4 tail blocks first: frame 512 per batch). XCD swizzle: quads of
// consecutive blocks (16 pairs = one 128 B output-line span) share an XCD.
// Fallback if this fails or regresses: R20 (pinned, <42.8 us).

#define N_FFT   2048
#define HOP     512
#define PADL    1024
#define NBINS   1025
#define NFRAMES 513
#define NBATCH  16
#define TLEN    262144

#define HALF_OUT ((size_t)NBATCH * NBINS * NFRAMES)   // 8,413,200 floats per plane

typedef float f2_t __attribute__((ext_vector_type(2)));
typedef f2_t uf2 __attribute__((aligned(4)));         // 4B-aligned dwordx2

__device__ __forceinline__ int refl(int j) {
    if (j < 0)          j = -j;
    else if (j >= TLEN) j = 2 * TLEN - 2 - j;
    return j;
}

__device__ __forceinline__ float2 cmul(float2 a, float2 w) {
    return make_float2(fmaf(a.x, w.x, -a.y * w.y), fmaf(a.x, w.y, a.y * w.x));
}
__device__ __forceinline__ float2 cadd(float2 a, float2 b) {
    return make_float2(a.x + b.x, a.y + b.y);
}
__device__ __forceinline__ float2 csub(float2 a, float2 b) {
    return make_float2(a.x - b.x, a.y - b.y);
}

// 5-bit bit reversal (compile-time in unrolled loops)
__device__ __forceinline__ constexpr int BR5(int v) {
    return ((v & 1) << 4) | ((v & 2) << 2) | (v & 4) | ((v & 8) >> 2) | ((v & 16) >> 4);
}

__global__ __launch_bounds__(256) void stft_one(
    const float* __restrict__ x,
    const float* __restrict__ window,
    float* __restrict__ out)
{
    const int d   = blockIdx.x;
    const int tid = threadIdx.x;
    const int wv  = tid >> 6;       // wave in block [0,4)
    const int l   = tid & 63;       // lane = n1

    // ---- wave -> (batch, pair) mapping ----
    int b, pr; bool tail;
    if (d < 4) {                    // 16 tail waves: frame 512 of batch b
        b = d * 4 + wv; pr = 0; tail = true;
    } else {
        tail = false;
        const int m    = d - 4;     // [0,1024)
        const int xcd  = m & 7;
        const int slot = m >> 3;                  // [0,128)
        const int Q    = (slot >> 2) * 8 + xcd;   // quad id [0,256)
        const int L    = Q * 4 + (slot & 3);      // logical block [0,1024)
        b  = L >> 6;                              // [0,16)
        pr = (L & 63) * 4 + wv;                   // pair [0,256)
    }
    const int fa = tail ? 512 : 2 * pr;           // even frame of the pair
    const int a0 = fa * HOP - PADL;
    const float* xb = x + (size_t)b * TLEN;

    // ---- load: z[n] = va + i*vb, n = l + 64r (coalesced per reg) ----
    float2 u[32];
    if (!tail && pr >= 1 && pr <= 254) {          // interior: refl() dead
#pragma unroll
        for (int r = 0; r < 32; ++r) {
            const int n = l + 64 * r;
            const float w = window[n];
            u[r] = make_float2(xb[a0 + n] * w, xb[a0 + 512 + n] * w);
        }
    } else {                                      // edges + tail: reflect
#pragma unroll
        for (int r = 0; r < 32; ++r) {
            const int n = l + 64 * r;
            const float w = window[n];
            u[r] = make_float2(xb[refl(a0 + n)] * w, xb[refl(a0 + 512 + n)] * w);
        }
    }

    // ---- step 1: 32-pt DIF FFT over regs (n2). Y(k2) lands at reg BR5(k2).
    {
        // W32^t = exp(-2*pi*i*t/32), t = j*(16/h)
        constexpr float WC[16] = {
            1.0f, 0.9807852804f, 0.9238795325f, 0.8314696123f,
            0.7071067812f, 0.5555702330f, 0.3826834324f, 0.1950903220f,
            0.0f, -0.1950903220f, -0.3826834324f, -0.5555702330f,
            -0.7071067812f, -0.8314696123f, -0.9238795325f, -0.9807852804f };
        constexpr float WS[16] = {
            -0.0f, -0.1950903220f, -0.3826834324f, -0.5555702330f,
            -0.7071067812f, -0.8314696123f, -0.9238795325f, -0.9807852804f,
            -1.0f, -0.9807852804f, -0.9238795325f, -0.8314696123f,
            -0.7071067812f, -0.5555702330f, -0.3826834324f, -0.1950903220f };
#pragma unroll
        for (int h = 16; h >= 1; h >>= 1) {
#pragma unroll
            for (int base = 0; base < 32; base += 2 * h) {
#pragma unroll
                for (int j = 0; j < h; ++j) {
                    const int i = base + j;
                    const float2 A = u[i], B = u[i + h];
                    const int t = j * (16 / h);
                    u[i]     = cadd(A, B);
                    u[i + h] = cmul(csub(A, B), make_float2(WC[t], WS[t]));
                }
            }
        }
    }

    // ---- step 2: twiddle W_2048^{l*k2} applied at reg BR5(k2) ----
    {
        float s1, c1;
        __sincosf(-3.14159265358979323846f / 1024.0f * (float)l, &s1, &c1);
        const float2 t1 = make_float2(c1, s1);    // exp(-2*pi*i*l/2048)
        float2 w = t1;
#pragma unroll
        for (int k2 = 1; k2 < 32; ++k2) {
            u[BR5(k2)] = cmul(u[BR5(k2)], w);
            w = cmul(w, t1);
        }
    }

    // ---- step 3: 64-pt DIF FFT across lanes (n1). k1 = bitrev6(lane). ----
#pragma unroll
    for (int h = 32; h >= 1; h >>= 1) {
        const int j = l & (h - 1);
        float s3, c3;
        __sincosf(-3.14159265358979323846f * (float)j / (float)h, &s3, &c3);
        const bool hi = (l & h) != 0;
        const float2 weff = hi ? make_float2(c3, s3) : make_float2(1.0f, 0.0f);
#pragma unroll
        for (int i = 0; i < 32; ++i) {
            const float2 p = make_float2(__shfl_xor(u[i].x, h),
                                         __shfl_xor(u[i].y, h));
            const float2 t = hi ? csub(p, u[i]) : cadd(u[i], p);
            u[i] = cmul(t, weff);
        }
    }

    // ---- step 4: conjugate-symmetry epilogue, all in-wave ----
    const int k1 = (int)(__brev((unsigned)l) >> 26);      // bitrev6(l)
    // k2==0 partner: X[2048-32*k1] = reg 0 of lane bitrev6((64-k1)&63)
    const int kk = (64 - k1) & 63;
    const int lp = (int)(__brev((unsigned)kk) >> 26);
    const float2 xr0 = make_float2(__shfl(u[0].x, lp), __shfl(u[0].y, lp));
    const bool ev = ((l & 1) == 0);                       // k1 <= 31
    float* __restrict__ outr = out;
    float* __restrict__ outi = out + HALF_OUT;

#pragma unroll
    for (int p = 0; p < 32; ++p) {
        const int k2 = BR5(p);
        float2 xr;
        if (p == 0) {
            xr = xr0;
        } else {
            // k2' = 32-k2 at reg BR5(32-k2); k1' = 63-k1 at lane l^63
            const int pp = BR5(32 - k2);
            xr = make_float2(__shfl_xor(u[pp].x, 63), __shfl_xor(u[pp].y, 63));
        }
        const float2 xk = u[p];
        const bool doSt = ev || (l == 1 && p == 0);       // lane1: k=1024
        if (doSt) {
            const int k = k2 + 32 * k1;
            const size_t o = ((size_t)b * NBINS + (size_t)k) * NFRAMES + (size_t)fa;
            if (!tail) {
                uf2 re, im;
                re.x = 0.5f * (xk.x + xr.x);   // even frame re
                re.y = 0.5f * (xk.y + xr.y);   // odd frame re
                im.x = 0.5f * (xk.y - xr.y);   // even frame im
                im.y = 0.5f * (xr.x - xk.x);   // odd frame im
                *reinterpret_cast<uf2*>(&outr[o]) = re;
                *reinterpret_cast<uf2*>(&outi[o]) = im;
            } else {
                outr[o] = 0.5f * (xk.x + xr.x);
                outi[o] = 0.5f * (xk.y - xr.y);
            }
        }
    }
}

extern "C" void kernel_launch(void* const* d_in, const int* in_sizes, int n_in,
                              void* d_out, int out_size, void* d_ws, size_t ws_size,
                              hipStream_t stream) {
    const float* x      = (const float*)d_in[0];
    const float* window = (const float*)d_in[1];
    float* out          = (float*)d_out;

    dim3 grid(1028);   // 4 tail blocks (first) + 1024 main; d_ws unused
    stft_one<<<grid, 256, 0, stream>>>(x, window, out);
}

// Round 15
// 102.976 us; speedup vs baseline: 1.3038x; 1.3038x over previous
//
#include <hip/hip_runtime.h>

// STFT: x[16, 262144] fp32, Hann 2048, hop 512, reflect pad 1024.
// Output: real[16,1025,513] ++ imag[16,1025,513], fp32.
//
// FINAL (== R18/R20, session best: <42.8 us kernel dispatch, 103.5 us bench,
// from 127.7 at session start). R21's register-resident shuffle-FFT probe
// regressed to 73.5 us (shfl routes through the DS pipe: ~450 DS-ops/thread
// vs ~80 here — cost model falsified) and was reverted per pre-commitment.
//
// Structure: 512 thr, 2 packed FFTs (4 frames), 33.8 KB LDS, 4 blocks/CU
// (measured optimum of the residency lever: 2/4/8 blk/CU -> 52/49/54.6 us).
//  - float4 interior loader (refl provably dead for g in [1,126];
//    brev11(4j+u) = brev9(j)+{0,1024,512,1536}[u]); scalar edge loader.
//  - Trips 1-3 wave-local (wave w: plane tid>>8, chunk (tid>>6)&3), synced
//    by wave-local s_waitcnt lgkmcnt(0)+sched_barrier; 3 block barriers.
//  - Shared-sincos radix-4 quad, 3-pass conjugate-symmetry epilogue,
//    octet XCD swizzle for 128B-line write merging, tail blocks first.
//
// Final lever ledger: residency bracketed; in-block overlap failed 3x
// (convoy R10 / spill R11 / L2+occ R12); work-diet 49->42.7 (R13) then flat
// (R16/R19); barrier-diet ~1us (R18); shuffle-FFT 73.5 (R21). Floor
// counters: HBM 28% / VALU 27% / LDS ~20% — structural latency floor of the
// barrier-phased chain at optimal residency, not a pipe roofline.

#define N_FFT   2048
#define LOG2N   11
#define HOP     512
#define PADL    1024
#define NBINS   1025
#define NFRAMES 513
#define NBATCH  16
#define TLEN    262144

#define HALF_OUT ((size_t)NBATCH * NBINS * NFRAMES)   // 8,413,200 floats per plane

// wave-local fence: my LDS ops done & visible to my own lanes; compiler must
// not hoist the following LDS ops above it.
#define WFENCE() do { \
    asm volatile("s_waitcnt lgkmcnt(0)" ::: "memory"); \
    __builtin_amdgcn_sched_barrier(0); \
} while (0)

__device__ __forceinline__ int pidx(int a) { return a + (a >> 5); }

__device__ __forceinline__ int refl(int j) {
    if (j < 0)          j = -j;
    else if (j >= TLEN) j = 2 * TLEN - 2 - j;
    return j;
}

__device__ __forceinline__ int brev11(int n) {
    return (int)(__brev((unsigned)n) >> 21);
}

__device__ __forceinline__ float2 cmul(float2 a, float2 w) {
    return make_float2(fmaf(a.x, w.x, -a.y * w.y), fmaf(a.x, w.y, a.y * w.x));
}
__device__ __forceinline__ float2 cadd(float2 a, float2 b) {
    return make_float2(a.x + b.x, a.y + b.y);
}
__device__ __forceinline__ float2 csub(float2 a, float2 b) {
    return make_float2(a.x - b.x, a.y - b.y);
}
__device__ __forceinline__ float2 csqr(float2 w) {
    return make_float2(fmaf(w.x, w.x, -w.y * w.y), 2.0f * w.x * w.y);
}

// Three DIT stages (halves H, 2H, 4H) on points base + m*H, m=0..7, in registers.
template <int H, int L2H>
__device__ __forceinline__ void octet_pass(float2* __restrict__ zc, int q) {
    const int p    = q & (H - 1);
    const int base = ((q >> L2H) << (L2H + 3)) + p;
    int ia[8];
#pragma unroll
    for (int m = 0; m < 8; ++m) ia[m] = pidx(base + m * H);
    float2 v0 = zc[ia[0]], v1 = zc[ia[1]], v2 = zc[ia[2]], v3 = zc[ia[3]];
    float2 v4 = zc[ia[4]], v5 = zc[ia[5]], v6 = zc[ia[6]], v7 = zc[ia[7]];

    float2 w1, w2, w3;
    if (H == 1) {
        w3 = make_float2(1.0f, 0.0f); w2 = w3; w1 = w3;   // p==0 always
    } else {
        float s, c;
        __sincosf((float)p * (-3.14159265358979323846f / (4.0f * (float)H)), &s, &c);
        w3 = make_float2(c, s);
        w2 = csqr(w3);
        w1 = csqr(w2);
    }

    float2 t;
    // stage A (half=H): pairs (0,1)(2,3)(4,5)(6,7), all twiddle w1
    t = cmul(v1, w1); v1 = csub(v0, t); v0 = cadd(v0, t);
    t = cmul(v3, w1); v3 = csub(v2, t); v2 = cadd(v2, t);
    t = cmul(v5, w1); v5 = csub(v4, t); v4 = cadd(v4, t);
    t = cmul(v7, w1); v7 = csub(v6, t); v6 = cadd(v6, t);
    // stage B (half=2H): pairs (0,2)(4,6) w2 ; (1,3)(5,7) -i*w2
    const float2 w2m = make_float2(w2.y, -w2.x);
    t = cmul(v2, w2);  v2 = csub(v0, t); v0 = cadd(v0, t);
    t = cmul(v3, w2m); v3 = csub(v1, t); v1 = cadd(v1, t);
    t = cmul(v6, w2);  v6 = csub(v4, t); v4 = cadd(v4, t);
    t = cmul(v7, w2m); v7 = csub(v5, t); v5 = cadd(v5, t);
    // stage C (half=4H): pairs (0,4) w3 ; (1,5) w3*e^{-i pi/4} ; (2,6) -i*w3 ; (3,7) -i*w3*e^{-i pi/4}
    const float R = 0.70710678118654752f;
    const float2 w3o  = make_float2((w3.x + w3.y) * R, (w3.y - w3.x) * R);
    const float2 w3m  = make_float2(w3.y, -w3.x);
    const float2 w3mo = make_float2(w3o.y, -w3o.x);
    t = cmul(v4, w3);   v4 = csub(v0, t); v0 = cadd(v0, t);
    t = cmul(v5, w3o);  v5 = csub(v1, t); v1 = cadd(v1, t);
    t = cmul(v6, w3m);  v6 = csub(v2, t); v2 = cadd(v2, t);
    t = cmul(v7, w3mo); v7 = csub(v3, t); v3 = cadd(v3, t);

    zc[ia[0]] = v0; zc[ia[1]] = v1; zc[ia[2]] = v2; zc[ia[3]] = v3;
    zc[ia[4]] = v4; zc[ia[5]] = v5; zc[ia[6]] = v6; zc[ia[7]] = v7;
}

// Radix-4 quad item (stages 10-11, h=512), twiddles precomputed by caller.
__device__ __forceinline__ void quad_core(float2* __restrict__ zc, int p,
                                          float2 w1, float2 w2, float2 w2m) {
    const int i0 = pidx(p), i1 = pidx(p + 512), i2 = pidx(p + 1024), i3 = pidx(p + 1536);
    float2 v0 = zc[i0], v1 = zc[i1], v2 = zc[i2], v3 = zc[i3];
    float2 t;
    t = cmul(v1, w1); v1 = csub(v0, t); v0 = cadd(v0, t);
    t = cmul(v3, w1); v3 = csub(v2, t); v2 = cadd(v2, t);
    t = cmul(v2, w2);  v2 = csub(v0, t); v0 = cadd(v0, t);
    t = cmul(v3, w2m); v3 = csub(v1, t); v1 = cadd(v1, t);
    zc[i0] = v0; zc[i1] = v1; zc[i2] = v2; zc[i3] = v3;
}

__global__ __launch_bounds__(512, 8) void stft_one(
    const float* __restrict__ x,
    const float* __restrict__ window,
    float* __restrict__ out)
{
    __shared__ float2 z[2][2113];     // 33,808 B -> 4 blocks/CU

    const int d   = blockIdx.x;
    const int tid = threadIdx.x;
    float* __restrict__ outr = out;
    float* __restrict__ outi = out + HALF_OUT;

    // ---------------- tail blocks: frame 512 of batch d, run first ----------
    if (d < NBATCH) {
        const int b = d;
        const float* xb = x + (size_t)b * TLEN;
        const int a0 = 512 * HOP - PADL;
#pragma unroll
        for (int it = 0; it < 4; ++it) {
            const int n = tid + it * 512;
            const float w  = window[n];
            const float va = xb[refl(a0 + n)] * w;
            const float vb = xb[refl(a0 + HOP + n)] * w;   // phantom frame, unused
            z[0][pidx(brev11(n))] = make_float2(va, vb);
        }
        __syncthreads();
        if (tid < 256) octet_pass<1, 0>(z[0], tid);
        __syncthreads();
        if (tid < 256) octet_pass<8, 3>(z[0], tid);
        __syncthreads();
        if (tid < 256) octet_pass<64, 6>(z[0], tid);
        __syncthreads();
        {
            float s, cc;
            __sincosf((float)tid * (-3.14159265358979323846f / 1024.0f), &s, &cc);
            const float2 w2  = make_float2(cc, s);
            const float2 w1  = csqr(w2);
            const float2 w2m = make_float2(w2.y, -w2.x);
            quad_core(z[0], tid, w1, w2, w2m);
        }
        __syncthreads();
#pragma unroll
        for (int it = 0; it < 3; ++it) {
            const int k = tid + it * 512;
            if (k < NBINS) {
                const int km = (N_FFT - k) & (N_FFT - 1);
                const float2 zk = z[0][pidx(k)];
                const float2 zr = z[0][pidx(km)];
                const size_t o = ((size_t)b * NBINS + (size_t)k) * NFRAMES + 512;
                outr[o] = 0.5f * (zk.x + zr.x);
                outi[o] = 0.5f * (zk.y - zr.y);
            }
        }
        return;
    }

    // ---------------- main blocks ----------------
    // XCD swizzle: octets of consecutive g (one 128 B output-line span) get
    // ids differing by 8 (same XCD) in adjacent slots (co-resident).
    const int m    = d - NBATCH;                  // [0,2048)
    const int xcd  = m & 7;
    const int slot = m >> 3;                      // [0,256)
    const int O    = (slot >> 3) * 8 + xcd;       // octet id [0,256)
    const int L    = O * 8 + (slot & 7);          // logical block [0,2048)
    const int b    = L >> 7;
    const int g    = L & 127;
    const int f0   = g * 4;

    const float* xb = x + (size_t)b * TLEN;

    // ---- load 4 windowed frames (2 planes), bit-reversed ----
    if (g >= 1 && g <= 126) {
        // interior: refl() dead (span [1024, 260607]); all 16B-aligned.
#pragma unroll
        for (int it = 0; it < 2; ++it) {
            const int idx = tid + it * 512;       // [0,1024)
            const int c   = idx >> 9;
            const int j   = idx & 511;
            const int n0  = j << 2;
            const int a0  = (f0 + 2 * c) * HOP - PADL;
            const float4 w4 = *reinterpret_cast<const float4*>(&window[n0]);
            const float4 a4 = *reinterpret_cast<const float4*>(&xb[a0 + n0]);
            const float4 b4 = *reinterpret_cast<const float4*>(&xb[a0 + HOP + n0]);
            const int r0 = (int)(__brev((unsigned)j) >> 23);   // brev9(j)
            // brev11(4j+u) = brev9(j) + {0,1024,512,1536}[u]
            z[c][pidx(r0)]        = make_float2(a4.x * w4.x, b4.x * w4.x);
            z[c][pidx(r0 + 1024)] = make_float2(a4.y * w4.y, b4.y * w4.y);
            z[c][pidx(r0 + 512)]  = make_float2(a4.z * w4.z, b4.z * w4.z);
            z[c][pidx(r0 + 1536)] = make_float2(a4.w * w4.w, b4.w * w4.w);
        }
    } else {
        // edge blocks (g==0, g==127): scalar refl path
#pragma unroll
        for (int it = 0; it < 8; ++it) {
            const int idx = tid + it * 512;       // [0,4096)
            const int c   = idx >> 11;
            const int n   = idx & 2047;
            const int fa  = f0 + 2 * c;
            const float w  = window[n];
            const float va = xb[refl(fa * HOP - PADL + n)] * w;
            const float vb = xb[refl((fa + 1) * HOP - PADL + n)] * w;
            z[c][pidx(brev11(n))] = make_float2(va, vb);
        }
    }
    __syncthreads();

    // ---- stages 1-9: three radix-8 register trips, wave-local sync ----
    // Wave w: plane tid>>8, 512-pt chunk (tid>>6)&3 — each trip touches only
    // that chunk, so inter-trip sync is wave-local (verified R10/R18).
    {
        const int c = tid >> 8, q = tid & 255;
        octet_pass<1, 0>(z[c], q);  WFENCE();
        octet_pass<8, 3>(z[c], q);  WFENCE();
        octet_pass<64, 6>(z[c], q); __syncthreads();   // quad crosses chunks
    }

    // ---- stages 10-11: radix-4 quad pass (h=512), twiddles shared ----
    {
        const int p = tid;                        // [0,512)
        float s, cc;
        __sincosf((float)p * (-3.14159265358979323846f / 1024.0f), &s, &cc);
        const float2 w2  = make_float2(cc, s);    // exp(-i*pi*p/1024)
        const float2 w1  = csqr(w2);              // exp(-i*pi*p/512)
        const float2 w2m = make_float2(w2.y, -w2.x);
        quad_core(z[0], p, w1, w2, w2m);
        quad_core(z[1], p, w1, w2, w2m);
    }
    __syncthreads();

    // ---- unpack + direct write: 16 B chunk per k-row ----
#pragma unroll
    for (int it = 0; it < 3; ++it) {
        const int k = tid + it * 512;
        if (k < NBINS) {
            const int km = (N_FFT - k) & (N_FFT - 1);
            const float2 zk0 = z[0][pidx(k)];
            const float2 zr0 = z[0][pidx(km)];
            const float2 zk1 = z[1][pidx(k)];
            const float2 zr1 = z[1][pidx(km)];
            const size_t o = ((size_t)b * NBINS + (size_t)k) * NFRAMES + (size_t)f0;
            outr[o + 0] = 0.5f * (zk0.x + zr0.x);   // even frame re
            outr[o + 1] = 0.5f * (zk0.y + zr0.y);   // odd frame re
            outr[o + 2] = 0.5f * (zk1.x + zr1.x);
            outr[o + 3] = 0.5f * (zk1.y + zr1.y);
            outi[o + 0] = 0.5f * (zk0.y - zr0.y);   // even frame im
            outi[o + 1] = 0.5f * (zr0.x - zk0.x);   // odd frame im
            outi[o + 2] = 0.5f * (zk1.y - zr1.y);
            outi[o + 3] = 0.5f * (zr1.x - zk1.x);
        }
    }
}

extern "C" void kernel_launch(void* const* d_in, const int* in_sizes, int n_in,
                              void* d_out, int out_size, void* d_ws, size_t ws_size,
                              hipStream_t stream) {
    const float* x      = (const float*)d_in[0];
    const float* window = (const float*)d_in[1];
    float* out          = (float*)d_out;

    dim3 grid(2064);   // 16 tail (first) + 2048 main; d_ws deliberately unused
    stft_one<<<grid, 512, 0, stream>>>(x, window, out);
}